// Round 3
// baseline (321.714 us; speedup 1.0000x reference)
//
#include <hip/hip_runtime.h>
#include <hip/hip_bf16.h>
#include <math.h>

// Problem constants
#define SEQ 4096
#define DM  1024
#define NIMU 72
#define NNOISE 12
#define NJ (NIMU*NNOISE)     // 864
#define TSTEPS 300
#define PLANE (NIMU*SEQ)     // 294912
#define KP 2048              // A2 / Bt row length in bf16: [hi(1024) | lo(1024)]

// Workspace layout (34.5 MB):
//   A2 : 4096 x 2048 bf16  (LayerNormed x, hi|lo split)           16.78 MB
//   Bt : 864  x 2048 bf16  (W^T, hi|lo split, j-major)             3.54 MB
//   pt : 864  x 4096 f32   (P^T, bias-initialized, atomic-accum)  14.16 MB
// (OOB B-tile reads for j in [864,896) land harmlessly in pt.)

typedef __attribute__((ext_vector_type(8))) short bf16x8;
typedef __attribute__((ext_vector_type(4))) float f32x4;

__device__ __forceinline__ void async16(const void* g, void* l) {
    __builtin_amdgcn_global_load_lds(
        (const __attribute__((address_space(1))) void*)g,
        (__attribute__((address_space(3))) void*)l, 16, 0, 0);
}

__device__ __forceinline__ float softplus_f(float x) {
    return fmaxf(x, 0.f) + log1pf(expf(-fabsf(x)));
}

// round-to-nearest-even bf16 split: x ~= hi + lo with |err| ~ 2^-16 * |x|
__device__ __forceinline__ void split_bf16(float x, short& hi, short& lo) {
    unsigned b = __float_as_uint(x);
    unsigned h = (b + 0x7FFFu + ((b >> 16) & 1u)) >> 16;
    float hf = __uint_as_float(h << 16);
    float r = x - hf;
    unsigned b2 = __float_as_uint(r);
    unsigned l2 = (b2 + 0x7FFFu + ((b2 >> 16) & 1u)) >> 16;
    hi = (short)h;
    lo = (short)l2;
}

// ---------------- 1. LayerNorm -> A2 (bf16 hi|lo) ----------------
__global__ __launch_bounds__(256) void ln_kernel(const float* __restrict__ x,
                                                 const float* __restrict__ gamma,
                                                 const float* __restrict__ beta,
                                                 short* __restrict__ A2) {
    const int row = blockIdx.x;
    const int tid = threadIdx.x;
    const float4* xr = (const float4*)(x + (size_t)row * DM);
    float4 v = xr[tid];
    float s  = v.x + v.y + v.z + v.w;
    float sq = v.x*v.x + v.y*v.y + v.z*v.z + v.w*v.w;
    #pragma unroll
    for (int off = 32; off > 0; off >>= 1) {
        s  += __shfl_xor(s, off);
        sq += __shfl_xor(sq, off);
    }
    __shared__ float ls[4], lq[4];
    __shared__ float mean_s, rstd_s;
    const int wid = tid >> 6, lane = tid & 63;
    if (lane == 0) { ls[wid] = s; lq[wid] = sq; }
    __syncthreads();
    if (tid == 0) {
        float ts = ls[0] + ls[1] + ls[2] + ls[3];
        float tq = lq[0] + lq[1] + lq[2] + lq[3];
        float mean = ts * (1.f / DM);
        float var  = tq * (1.f / DM) - mean * mean;
        mean_s = mean;
        rstd_s = rsqrtf(fmaxf(var, 0.f) + 1e-5f);
    }
    __syncthreads();
    const float mean = mean_s, rstd = rstd_s;
    float4 g = ((const float4*)gamma)[tid];
    float4 b = ((const float4*)beta)[tid];
    float o[4];
    o[0] = (v.x - mean) * rstd * g.x + b.x;
    o[1] = (v.y - mean) * rstd * g.y + b.y;
    o[2] = (v.z - mean) * rstd * g.z + b.z;
    o[3] = (v.w - mean) * rstd * g.w + b.w;
    short4 hv, lv;
    split_bf16(o[0], hv.x, lv.x);
    split_bf16(o[1], hv.y, lv.y);
    split_bf16(o[2], hv.z, lv.z);
    split_bf16(o[3], hv.w, lv.w);
    short* rowp = A2 + (size_t)row * KP;
    *(short4*)(rowp + 4 * tid)        = hv;
    *(short4*)(rowp + 1024 + 4 * tid) = lv;
}

// ---------------- 2a. W -> Bt (transpose + bf16 hi|lo) ----------------
__global__ __launch_bounds__(256) void wprep_kernel(const float* __restrict__ W,
                                                    short* __restrict__ Bt) {
    __shared__ float T[32][33];
    const int k0 = blockIdx.x * 32, j0 = blockIdx.y * 32;
    const int t = threadIdx.x;
    const int r = t >> 3, c4 = (t & 7) * 4;
    float4 v = *(const float4*)(W + (size_t)(k0 + r) * NJ + j0 + c4);
    T[r][c4 + 0] = v.x; T[r][c4 + 1] = v.y; T[r][c4 + 2] = v.z; T[r][c4 + 3] = v.w;
    __syncthreads();
    const int jr = r, kc = c4;
    short4 hv, lv;
    split_bf16(T[kc + 0][jr], hv.x, lv.x);
    split_bf16(T[kc + 1][jr], hv.y, lv.y);
    split_bf16(T[kc + 2][jr], hv.z, lv.z);
    split_bf16(T[kc + 3][jr], hv.w, lv.w);
    short* rowp = Bt + (size_t)(j0 + jr) * KP;
    *(short4*)(rowp + k0 + kc)        = hv;
    *(short4*)(rowp + 1024 + k0 + kc) = lv;
}

// ---------------- 2b. pt init with bias ----------------
__global__ __launch_bounds__(256) void initpt_kernel(const float* __restrict__ b,
                                                     float* __restrict__ pt) {
    const int j = blockIdx.x;
    const float bj = b[j];
    float4 v = {bj, bj, bj, bj};
    float4* row = (float4*)(pt + (size_t)j * SEQ);
    for (int i = threadIdx.x; i < SEQ / 4; i += 256) row[i] = v;
}

// ---------------- 2c. MFMA GEMM: pt[j,s] += seg-term of (xn @ W)^T ----------------
// 128(s) x 128(j) tile, BK=32, 256 thr = 4 waves, wave tile 64x64 (4x4 of 16x16x32).
// Frag-linear LDS (tile slot = 1KB, lane l's 16B at +l*16) staged via
// global_load_lds width=16. split-K=3 over (xh*wh, xh*wl, xl*wh) via blockIdx.z;
// fp32 atomicAdd epilogue into bias-initialized pt.
__global__ __launch_bounds__(256) void gemm_kernel(const short* __restrict__ A2,
                                                   const short* __restrict__ Bt,
                                                   float* __restrict__ pt) {
    __shared__ short As[4096];   // 8 tile-slots x 512 shorts
    __shared__ short Bs[4096];
    const int tid = threadIdx.x;
    const int l = tid & 63, w = tid >> 6;
    const int s0 = blockIdx.x * 128;
    const int j0 = blockIdx.y * 128;
    const int seg = blockIdx.z;
    const int aoff = (seg == 2) ? 1024 : 0;   // xl for seg2
    const int boff = (seg == 1) ? 1024 : 0;   // wl for seg1

    const int lm = l & 15;       // fragment row (m or n)
    const int lc = l >> 4;       // k-chunk of 8

    // staging: wave w loads A-tiles {2w,2w+1} and B-tiles {2w,2w+1}
    const short* gA0 = A2 + (size_t)(s0 + (2*w+0)*16 + lm) * KP + aoff + lc*8;
    const short* gA1 = A2 + (size_t)(s0 + (2*w+1)*16 + lm) * KP + aoff + lc*8;
    const short* gB0 = Bt + (size_t)(j0 + (2*w+0)*16 + lm) * KP + boff + lc*8;
    const short* gB1 = Bt + (size_t)(j0 + (2*w+1)*16 + lm) * KP + boff + lc*8;
    short* lA0 = As + (2*w+0)*512;
    short* lA1 = As + (2*w+1)*512;
    short* lB0 = Bs + (2*w+0)*512;
    short* lB1 = Bs + (2*w+1)*512;

    const int mh = (w & 1) * 4;   // wave's m-tile base
    const int nh = (w >> 1) * 4;  // wave's n-tile base
    const short* fA = As + mh * 512 + l * 8;
    const short* fB = Bs + nh * 512 + l * 8;

    f32x4 acc[4][4] = {};

    for (int kt = 0; kt < 32; ++kt) {
        async16(gA0, lA0); async16(gA1, lA1);
        async16(gB0, lB0); async16(gB1, lB1);
        gA0 += 32; gA1 += 32; gB0 += 32; gB1 += 32;
        __syncthreads();
        bf16x8 a[4], b[4];
        #pragma unroll
        for (int i = 0; i < 4; ++i) a[i] = *(const bf16x8*)(fA + i * 512);
        #pragma unroll
        for (int i = 0; i < 4; ++i) b[i] = *(const bf16x8*)(fB + i * 512);
        #pragma unroll
        for (int mi = 0; mi < 4; ++mi)
            #pragma unroll
            for (int ni = 0; ni < 4; ++ni)
                acc[mi][ni] = __builtin_amdgcn_mfma_f32_16x16x32_bf16(
                    a[mi], b[ni], acc[mi][ni], 0, 0, 0);
        __syncthreads();
    }

    // epilogue: C/D layout col=lane&15 (j), row=(lane>>4)*4+reg (s)  [m89]
    const int srow = (l >> 4) * 4;
    const int jcol = l & 15;
    #pragma unroll
    for (int ni = 0; ni < 4; ++ni) {
        int j = j0 + (nh + ni) * 16 + jcol;
        if (j < NJ) {
            #pragma unroll
            for (int mi = 0; mi < 4; ++mi) {
                float* dst = pt + (size_t)j * SEQ + s0 + (mh + mi) * 16 + srow;
                #pragma unroll
                for (int r = 0; r < 4; ++r)
                    atomicAdd(dst + r, acc[mi][ni][r]);
            }
        }
    }
}

// ---------------- 3. Spring recurrence + register diagonal scatter ----------------
__global__ __launch_bounds__(256) void spring_kernel(const float* __restrict__ pt,
                                                     float* __restrict__ kin) {
    const int tid  = threadIdx.x;
    const int lane = tid & 63;
    const int wid  = tid >> 6;
    const int s0   = blockIdx.x * 256;
    const int imu  = blockIdx.y;
    const int sbase = s0 + (wid << 6);
    const int s    = sbase + lane;

    const int base = imu * SEQ + s;
    const float p0  = pt[(size_t)0 * PLANE + base];
    const float p1  = pt[(size_t)1 * PLANE + base];
    const float p2  = pt[(size_t)2 * PLANE + base];
    const float p3  = pt[(size_t)3 * PLANE + base];
    const float c1  = pt[(size_t)4 * PLANE + base];
    const float c2  = pt[(size_t)5 * PLANE + base];
    const float ph1 = pt[(size_t)6 * PLANE + base];
    const float ph2 = pt[(size_t)7 * PLANE + base];

    float dd = softplus_f(p1);
    float kk = dd * dd * 0.25f + softplus_f(p0);
    float om1 = 0.5f * sqrtf(fmaxf(4.f * kk - dd * dd, 0.f));
    float dt = softplus_f(p3);
    float kt = dt * dt * 0.25f + softplus_f(p2);
    float om2 = 0.5f * sqrtf(fmaxf(4.f * kt - dt * dt, 0.f));
    float e1 = expf(-0.5f * dd), e2 = expf(-0.5f * dt);
    float sn, cs;
    sincosf(om1, &sn, &cs); const float mr1 = e1 * cs, mi1 = e1 * sn;
    sincosf(om2, &sn, &cs); const float mr2 = e2 * cs, mi2 = e2 * sn;
    sincosf(ph1, &sn, &cs); float im1 = c1 * sn, re1 = c1 * cs;
    sincosf(ph2, &sn, &cs); float im2 = c2 * sn, re2 = c2 * cs;

    float A[6];
    #pragma unroll
    for (int r = 0; r < 6; ++r) A[r] = 0.f;

    const bool full = (sbase + 64 + TSTEPS <= SEQ);   // wave-uniform

    if (full) {
        // static unroll: 4-deep bpermute batches, static accumulator indices
        #pragma unroll
        for (int tq = 0; tq < 5; ++tq) {
            const int trmax = (tq == 4) ? 44 : 64;   // 300 = 4*64 + 44
            for (int tr0 = 0; tr0 < trmax; tr0 += 4) {
                #pragma unroll
                for (int i = 0; i < 4; ++i) {
                    const int tr = tr0 + i;
                    float u = __shfl(im1 + im2, (lane - tr) & 63);
                    A[tq]     += (lane >= tr) ? u : 0.f;
                    A[tq + 1] += (lane <  tr) ? u : 0.f;
                    float r1 = fmaf(re1, mr1, -im1 * mi1);
                    im1 = fmaf(re1, mi1, im1 * mr1);
                    re1 = r1;
                    float r2 = fmaf(re2, mr2, -im2 * mi2);
                    im2 = fmaf(re2, mi2, im2 * mr2);
                    re2 = r2;
                }
            }
        }
    } else {
        const int tmax_wave = min(TSTEPS, SEQ - sbase);
        const int tmax_lane = SEQ - s;
        #pragma unroll
        for (int tq = 0; tq < 5; ++tq) {
            const int trmax = min(64, tmax_wave - tq * 64);
            for (int tr = 0; tr < trmax; ++tr) {
                const int t = tq * 64 + tr;
                float val = (t < tmax_lane) ? (im1 + im2) : 0.f;
                float u = __shfl(val, (lane - tr) & 63);
                A[tq]     += (lane >= tr) ? u : 0.f;
                A[tq + 1] += (lane <  tr) ? u : 0.f;
                float r1 = fmaf(re1, mr1, -im1 * mi1);
                im1 = fmaf(re1, mi1, im1 * mr1);
                re1 = r1;
                float r2 = fmaf(re2, mr2, -im2 * mi2);
                im2 = fmaf(re2, mi2, im2 * mr2);
                re2 = r2;
            }
            if (trmax < 64) break;
        }
    }

    #pragma unroll
    for (int r = 0; r < 6; ++r) {
        int pos = sbase + 64 * r + lane;
        if (pos < SEQ) {
            __hip_atomic_fetch_add(&kin[(size_t)imu * SEQ + pos], A[r],
                                   __ATOMIC_RELAXED, __HIP_MEMORY_SCOPE_AGENT);
        }
    }
}

// ---------------- 4. acc/gyro base & std outputs ----------------
__global__ __launch_bounds__(256) void tail_kernel(const float* __restrict__ pt,
                                                   float* __restrict__ out) {
    int idx = blockIdx.x * 256 + threadIdx.x;
    if (idx >= 4 * PLANE) return;
    float v = pt[(size_t)8 * PLANE + idx];
    int q = idx / PLANE;
    if (q & 1) v = softplus_f(v);
    out[(size_t)PLANE + idx] = v;
}

extern "C" void kernel_launch(void* const* d_in, const int* in_sizes, int n_in,
                              void* d_out, int out_size, void* d_ws, size_t ws_size,
                              hipStream_t stream) {
    const float* hs    = (const float*)d_in[0];
    const float* gamma = (const float*)d_in[1];
    const float* beta  = (const float*)d_in[2];
    const float* W     = (const float*)d_in[3];
    const float* b     = (const float*)d_in[4];
    float* out = (float*)d_out;

    short* A2 = (short*)d_ws;                         // 4096*2048 bf16
    short* Bt = A2 + (size_t)SEQ * KP;                // 864*2048 bf16
    float* pt = (float*)(Bt + (size_t)NJ * KP);       // 864*4096 f32

    hipMemsetAsync(out, 0, (size_t)PLANE * sizeof(float), stream);

    initpt_kernel<<<NJ, 256, 0, stream>>>(b, pt);
    wprep_kernel<<<dim3(DM / 32, NJ / 32), 256, 0, stream>>>(W, Bt);
    ln_kernel<<<SEQ, 256, 0, stream>>>(hs, gamma, beta, A2);
    gemm_kernel<<<dim3(SEQ / 128, 7, 3), 256, 0, stream>>>(A2, Bt, pt);
    spring_kernel<<<dim3(SEQ / 256, NIMU), 256, 0, stream>>>(pt, out);
    tail_kernel<<<(4 * PLANE + 255) / 256, 256, 0, stream>>>(pt, out);
}

// Round 4
// 219.497 us; speedup vs baseline: 1.4657x; 1.4657x over previous
//
#include <hip/hip_runtime.h>
#include <hip/hip_bf16.h>
#include <math.h>

// Problem constants
#define SEQ 4096
#define DM  1024
#define NIMU 72
#define NNOISE 12
#define NJ (NIMU*NNOISE)     // 864
#define TSTEPS 300
#define PLANE (NIMU*SEQ)     // 294912
#define KP 2048              // A2 / Bt row length in bf16: [hi(1024) | lo(1024)]

// Workspace layout (34.5 MB):
//   A2 : 4096 x 2048 bf16  (LayerNormed x, hi|lo split)   16.78 MB
//   Bt : 864  x 2048 bf16  (W^T, hi|lo split, j-major)     3.54 MB
//   pt : 864  x 4096 f32   (P^T)                          14.16 MB
// (OOB B-tile reads for j in [864,896) land harmlessly in pt; results discarded.)

typedef __attribute__((ext_vector_type(8))) short bf16x8;
typedef __attribute__((ext_vector_type(4))) float f32x4;

__device__ __forceinline__ void async16(const void* g, void* l) {
    __builtin_amdgcn_global_load_lds(
        (const __attribute__((address_space(1))) void*)g,
        (__attribute__((address_space(3))) void*)l, 16, 0, 0);
}

__device__ __forceinline__ float softplus_f(float x) {
    return fmaxf(x, 0.f) + log1pf(expf(-fabsf(x)));
}

// round-to-nearest-even bf16 split: x ~= hi + lo with |err| ~ 2^-16 * |x|
__device__ __forceinline__ void split_bf16(float x, short& hi, short& lo) {
    unsigned b = __float_as_uint(x);
    unsigned h = (b + 0x7FFFu + ((b >> 16) & 1u)) >> 16;
    float hf = __uint_as_float(h << 16);
    float r = x - hf;
    unsigned b2 = __float_as_uint(r);
    unsigned l2 = (b2 + 0x7FFFu + ((b2 >> 16) & 1u)) >> 16;
    hi = (short)h;
    lo = (short)l2;
}

// ---------------- 1. LayerNorm -> A2 (bf16 hi|lo) ----------------
__global__ __launch_bounds__(256) void ln_kernel(const float* __restrict__ x,
                                                 const float* __restrict__ gamma,
                                                 const float* __restrict__ beta,
                                                 short* __restrict__ A2) {
    const int row = blockIdx.x;
    const int tid = threadIdx.x;
    const float4* xr = (const float4*)(x + (size_t)row * DM);
    float4 v = xr[tid];
    float s  = v.x + v.y + v.z + v.w;
    float sq = v.x*v.x + v.y*v.y + v.z*v.z + v.w*v.w;
    #pragma unroll
    for (int off = 32; off > 0; off >>= 1) {
        s  += __shfl_xor(s, off);
        sq += __shfl_xor(sq, off);
    }
    __shared__ float ls[4], lq[4];
    __shared__ float mean_s, rstd_s;
    const int wid = tid >> 6, lane = tid & 63;
    if (lane == 0) { ls[wid] = s; lq[wid] = sq; }
    __syncthreads();
    if (tid == 0) {
        float ts = ls[0] + ls[1] + ls[2] + ls[3];
        float tq = lq[0] + lq[1] + lq[2] + lq[3];
        float mean = ts * (1.f / DM);
        float var  = tq * (1.f / DM) - mean * mean;
        mean_s = mean;
        rstd_s = rsqrtf(fmaxf(var, 0.f) + 1e-5f);
    }
    __syncthreads();
    const float mean = mean_s, rstd = rstd_s;
    float4 g = ((const float4*)gamma)[tid];
    float4 b = ((const float4*)beta)[tid];
    float o[4];
    o[0] = (v.x - mean) * rstd * g.x + b.x;
    o[1] = (v.y - mean) * rstd * g.y + b.y;
    o[2] = (v.z - mean) * rstd * g.z + b.z;
    o[3] = (v.w - mean) * rstd * g.w + b.w;
    short4 hv, lv;
    split_bf16(o[0], hv.x, lv.x);
    split_bf16(o[1], hv.y, lv.y);
    split_bf16(o[2], hv.z, lv.z);
    split_bf16(o[3], hv.w, lv.w);
    short* rowp = A2 + (size_t)row * KP;
    *(short4*)(rowp + 4 * tid)        = hv;
    *(short4*)(rowp + 1024 + 4 * tid) = lv;
}

// ---------------- 2a. W -> Bt (transpose + bf16 hi|lo) ----------------
__global__ __launch_bounds__(256) void wprep_kernel(const float* __restrict__ W,
                                                    short* __restrict__ Bt) {
    __shared__ float T[32][33];
    const int k0 = blockIdx.x * 32, j0 = blockIdx.y * 32;
    const int t = threadIdx.x;
    const int r = t >> 3, c4 = (t & 7) * 4;
    float4 v = *(const float4*)(W + (size_t)(k0 + r) * NJ + j0 + c4);
    T[r][c4 + 0] = v.x; T[r][c4 + 1] = v.y; T[r][c4 + 2] = v.z; T[r][c4 + 3] = v.w;
    __syncthreads();
    const int jr = r, kc = c4;
    short4 hv, lv;
    split_bf16(T[kc + 0][jr], hv.x, lv.x);
    split_bf16(T[kc + 1][jr], hv.y, lv.y);
    split_bf16(T[kc + 2][jr], hv.z, lv.z);
    split_bf16(T[kc + 3][jr], hv.w, lv.w);
    short* rowp = Bt + (size_t)(j0 + jr) * KP;
    *(short4*)(rowp + k0 + kc)        = hv;
    *(short4*)(rowp + 1024 + k0 + kc) = lv;
}

// ---------------- 2b. MFMA GEMM: pt[j,s] = ((xn @ W)^T + b), 3-term bf16 split ----------------
// 128(s) x 128(j) tile, BK=64, 48 K-iters = 3 segments (xh*wh, xh*wl, xl*wh) x 16.
// Double-buffered LDS (2 x 32KB), prefetch issued AFTER the barrier so the loads
// are in flight during compute (R3 failure: stage->barrier exposed full latency
// every iter -> MfmaUtil 4.3%). Plain float4-store epilogue (R3's atomicAdd
// epilogue dirtied 166 MB of HBM lines).
__global__ __launch_bounds__(256) void gemm_kernel(const short* __restrict__ A2,
                                                   const short* __restrict__ Bt,
                                                   const float* __restrict__ bias,
                                                   float* __restrict__ pt) {
    __shared__ short As[2][8192];   // 8 m-tiles x 2 k-slots x 512 shorts
    __shared__ short Bs[2][8192];
    const int tid = threadIdx.x;
    const int l = tid & 63, w = tid >> 6;
    const int s0 = blockIdx.x * 128;
    const int j0 = blockIdx.y * 128;
    const int lm = l & 15;          // fragment row within 16-row tile
    const int lc8 = (l >> 4) * 8;   // k-chunk offset (shorts) within 32-k slot

    // per-lane global base offsets (shorts) for the two tiles this wave stages
    const size_t baseA0 = (size_t)(s0 + (2*w+0)*16 + lm) * KP + lc8;
    const size_t baseA1 = (size_t)(s0 + (2*w+1)*16 + lm) * KP + lc8;
    const size_t baseB0 = (size_t)(j0 + (2*w+0)*16 + lm) * KP + lc8;
    const size_t baseB1 = (size_t)(j0 + (2*w+1)*16 + lm) * KP + lc8;

    const int mh = (w & 1) * 4;     // wave's m-tile base (tiles of 16 rows)
    const int nh = (w >> 1) * 4;    // wave's n-tile base

    f32x4 acc[4][4] = {};

    auto stage = [&](int buf, int kt) {
        const int seg = kt >> 4;
        const int ko  = (kt & 15) << 6;              // k offset within segment (shorts)
        const int offa = ko + ((seg == 2) ? 1024 : 0);   // xl for seg2
        const int offb = ko + ((seg == 1) ? 1024 : 0);   // wl for seg1
        short* la = &As[buf][(2*w) * 1024];
        short* lb = &Bs[buf][(2*w) * 1024];
        async16(A2 + baseA0 + offa,      la);
        async16(A2 + baseA0 + offa + 32, la + 512);
        async16(A2 + baseA1 + offa,      la + 1024);
        async16(A2 + baseA1 + offa + 32, la + 1536);
        async16(Bt + baseB0 + offb,      lb);
        async16(Bt + baseB0 + offb + 32, lb + 512);
        async16(Bt + baseB1 + offb,      lb + 1024);
        async16(Bt + baseB1 + offb + 32, lb + 1536);
    };

    stage(0, 0);
    for (int kt = 0; kt < 48; ++kt) {
        const int cur = kt & 1;
        __syncthreads();                      // drains loads for cur; prior compute done
        if (kt + 1 < 48) stage(cur ^ 1, kt + 1);   // prefetch in flight during compute
        const short* fA = &As[cur][mh * 1024 + l * 8];
        const short* fB = &Bs[cur][nh * 1024 + l * 8];
        bf16x8 a[4][2], b[4][2];
        #pragma unroll
        for (int mi = 0; mi < 4; ++mi) {
            a[mi][0] = *(const bf16x8*)(fA + mi * 1024);
            a[mi][1] = *(const bf16x8*)(fA + mi * 1024 + 512);
        }
        #pragma unroll
        for (int ni = 0; ni < 4; ++ni) {
            b[ni][0] = *(const bf16x8*)(fB + ni * 1024);
            b[ni][1] = *(const bf16x8*)(fB + ni * 1024 + 512);
        }
        #pragma unroll
        for (int mi = 0; mi < 4; ++mi)
            #pragma unroll
            for (int ni = 0; ni < 4; ++ni) {
                acc[mi][ni] = __builtin_amdgcn_mfma_f32_16x16x32_bf16(
                    a[mi][0], b[ni][0], acc[mi][ni], 0, 0, 0);
                acc[mi][ni] = __builtin_amdgcn_mfma_f32_16x16x32_bf16(
                    a[mi][1], b[ni][1], acc[mi][ni], 0, 0, 0);
            }
    }

    // epilogue: C/D layout col=lane&15 (j-within-tile), row=(lane>>4)*4+reg (s)
    const int srow = (l >> 4) * 4;
    const int jcol = l & 15;
    #pragma unroll
    for (int ni = 0; ni < 4; ++ni) {
        const int j = j0 + (nh + ni) * 16 + jcol;
        if (j < NJ) {
            const float bj = bias[j];
            #pragma unroll
            for (int mi = 0; mi < 4; ++mi) {
                f32x4 v = acc[mi][ni];
                v[0] += bj; v[1] += bj; v[2] += bj; v[3] += bj;
                *(f32x4*)(pt + (size_t)j * SEQ + s0 + (mh + mi) * 16 + srow) = v;
            }
        }
    }
}

// ---------------- 3. Spring recurrence + register diagonal scatter ----------------
__global__ __launch_bounds__(256) void spring_kernel(const float* __restrict__ pt,
                                                     float* __restrict__ kin) {
    const int tid  = threadIdx.x;
    const int lane = tid & 63;
    const int wid  = tid >> 6;
    const int s0   = blockIdx.x * 256;
    const int imu  = blockIdx.y;
    const int sbase = s0 + (wid << 6);
    const int s    = sbase + lane;

    const int base = imu * SEQ + s;
    const float p0  = pt[(size_t)0 * PLANE + base];
    const float p1  = pt[(size_t)1 * PLANE + base];
    const float p2  = pt[(size_t)2 * PLANE + base];
    const float p3  = pt[(size_t)3 * PLANE + base];
    const float c1  = pt[(size_t)4 * PLANE + base];
    const float c2  = pt[(size_t)5 * PLANE + base];
    const float ph1 = pt[(size_t)6 * PLANE + base];
    const float ph2 = pt[(size_t)7 * PLANE + base];

    float dd = softplus_f(p1);
    float kk = dd * dd * 0.25f + softplus_f(p0);
    float om1 = 0.5f * sqrtf(fmaxf(4.f * kk - dd * dd, 0.f));
    float dt = softplus_f(p3);
    float kt = dt * dt * 0.25f + softplus_f(p2);
    float om2 = 0.5f * sqrtf(fmaxf(4.f * kt - dt * dt, 0.f));
    float e1 = expf(-0.5f * dd), e2 = expf(-0.5f * dt);
    float sn, cs;
    sincosf(om1, &sn, &cs); const float mr1 = e1 * cs, mi1 = e1 * sn;
    sincosf(om2, &sn, &cs); const float mr2 = e2 * cs, mi2 = e2 * sn;
    sincosf(ph1, &sn, &cs); float im1 = c1 * sn, re1 = c1 * cs;
    sincosf(ph2, &sn, &cs); float im2 = c2 * sn, re2 = c2 * cs;

    float A[6];
    #pragma unroll
    for (int r = 0; r < 6; ++r) A[r] = 0.f;

    const bool full = (sbase + 64 + TSTEPS <= SEQ);   // wave-uniform

    if (full) {
        #pragma unroll
        for (int tq = 0; tq < 5; ++tq) {
            const int trmax = (tq == 4) ? 44 : 64;   // 300 = 4*64 + 44
            for (int tr0 = 0; tr0 < trmax; tr0 += 4) {
                #pragma unroll
                for (int i = 0; i < 4; ++i) {
                    const int tr = tr0 + i;
                    float u = __shfl(im1 + im2, (lane - tr) & 63);
                    A[tq]     += (lane >= tr) ? u : 0.f;
                    A[tq + 1] += (lane <  tr) ? u : 0.f;
                    float r1 = fmaf(re1, mr1, -im1 * mi1);
                    im1 = fmaf(re1, mi1, im1 * mr1);
                    re1 = r1;
                    float r2 = fmaf(re2, mr2, -im2 * mi2);
                    im2 = fmaf(re2, mi2, im2 * mr2);
                    re2 = r2;
                }
            }
        }
    } else {
        const int tmax_wave = min(TSTEPS, SEQ - sbase);
        const int tmax_lane = SEQ - s;
        #pragma unroll
        for (int tq = 0; tq < 5; ++tq) {
            const int trmax = min(64, tmax_wave - tq * 64);
            for (int tr = 0; tr < trmax; ++tr) {
                const int t = tq * 64 + tr;
                float val = (t < tmax_lane) ? (im1 + im2) : 0.f;
                float u = __shfl(val, (lane - tr) & 63);
                A[tq]     += (lane >= tr) ? u : 0.f;
                A[tq + 1] += (lane <  tr) ? u : 0.f;
                float r1 = fmaf(re1, mr1, -im1 * mi1);
                im1 = fmaf(re1, mi1, im1 * mr1);
                re1 = r1;
                float r2 = fmaf(re2, mr2, -im2 * mi2);
                im2 = fmaf(re2, mi2, im2 * mr2);
                re2 = r2;
            }
            if (trmax < 64) break;
        }
    }

    #pragma unroll
    for (int r = 0; r < 6; ++r) {
        int pos = sbase + 64 * r + lane;
        if (pos < SEQ) {
            __hip_atomic_fetch_add(&kin[(size_t)imu * SEQ + pos], A[r],
                                   __ATOMIC_RELAXED, __HIP_MEMORY_SCOPE_AGENT);
        }
    }
}

// ---------------- 4. acc/gyro base & std outputs ----------------
__global__ __launch_bounds__(256) void tail_kernel(const float* __restrict__ pt,
                                                   float* __restrict__ out) {
    int idx = blockIdx.x * 256 + threadIdx.x;
    if (idx >= 4 * PLANE) return;
    float v = pt[(size_t)8 * PLANE + idx];
    int q = idx / PLANE;
    if (q & 1) v = softplus_f(v);
    out[(size_t)PLANE + idx] = v;
}

extern "C" void kernel_launch(void* const* d_in, const int* in_sizes, int n_in,
                              void* d_out, int out_size, void* d_ws, size_t ws_size,
                              hipStream_t stream) {
    const float* hs    = (const float*)d_in[0];
    const float* gamma = (const float*)d_in[1];
    const float* beta  = (const float*)d_in[2];
    const float* W     = (const float*)d_in[3];
    const float* b     = (const float*)d_in[4];
    float* out = (float*)d_out;

    short* A2 = (short*)d_ws;                         // 4096*2048 bf16
    short* Bt = A2 + (size_t)SEQ * KP;                // 864*2048 bf16
    float* pt = (float*)(Bt + (size_t)NJ * KP);       // 864*4096 f32

    hipMemsetAsync(out, 0, (size_t)PLANE * sizeof(float), stream);

    wprep_kernel<<<dim3(DM / 32, NJ / 32), 256, 0, stream>>>(W, Bt);
    ln_kernel<<<SEQ, 256, 0, stream>>>(hs, gamma, beta, A2);
    gemm_kernel<<<dim3(SEQ / 128, 7), 256, 0, stream>>>(A2, Bt, b, pt);
    spring_kernel<<<dim3(SEQ / 256, NIMU), 256, 0, stream>>>(pt, out);
    tail_kernel<<<(4 * PLANE + 255) / 256, 256, 0, stream>>>(pt, out);
}

// Round 6
// 213.794 us; speedup vs baseline: 1.5048x; 1.0267x over previous
//
#include <hip/hip_runtime.h>
#include <hip/hip_bf16.h>
#include <math.h>

// Problem constants
#define SEQ 4096
#define DM  1024
#define NIMU 72
#define NNOISE 12
#define NJ (NIMU*NNOISE)     // 864
#define TSTEPS 300
#define PLANE (NIMU*SEQ)     // 294912
#define KP 2048              // A2 / Bt row length in bf16: [hi(1024) | lo(1024)]

// Workspace layout (34.5 MB):
//   A2 : 4096 x 2048 bf16  (LayerNormed x, hi|lo split)   16.78 MB
//   Bt : 864  x 2048 bf16  (W^T, hi|lo split, j-major)     3.54 MB
//   pt : 864  x 4096 f32   (P^T)                          14.16 MB
// (OOB B-tile reads for j in [864,896) land harmlessly in pt; results discarded.)

typedef __attribute__((ext_vector_type(8))) short bf16x8;
typedef __attribute__((ext_vector_type(4))) float f32x4;

__device__ __forceinline__ void async16(const void* g, void* l) {
    __builtin_amdgcn_global_load_lds(
        (const __attribute__((address_space(1))) void*)g,
        (__attribute__((address_space(3))) void*)l, 16, 0, 0);
}

__device__ __forceinline__ float softplus_f(float x) {
    return fmaxf(x, 0.f) + log1pf(expf(-fabsf(x)));
}

// round-to-nearest-even bf16 split: x ~= hi + lo with |err| ~ 2^-16 * |x|
__device__ __forceinline__ void split_bf16(float x, short& hi, short& lo) {
    unsigned b = __float_as_uint(x);
    unsigned h = (b + 0x7FFFu + ((b >> 16) & 1u)) >> 16;
    float hf = __uint_as_float(h << 16);
    float r = x - hf;
    unsigned b2 = __float_as_uint(r);
    unsigned l2 = (b2 + 0x7FFFu + ((b2 >> 16) & 1u)) >> 16;
    hi = (short)h;
    lo = (short)l2;
}

// ---------------- 1. LayerNorm -> A2 (bf16 hi|lo) ----------------
__global__ __launch_bounds__(256) void ln_kernel(const float* __restrict__ x,
                                                 const float* __restrict__ gamma,
                                                 const float* __restrict__ beta,
                                                 short* __restrict__ A2) {
    const int row = blockIdx.x;
    const int tid = threadIdx.x;
    const float4* xr = (const float4*)(x + (size_t)row * DM);
    float4 v = xr[tid];
    float s  = v.x + v.y + v.z + v.w;
    float sq = v.x*v.x + v.y*v.y + v.z*v.z + v.w*v.w;
    #pragma unroll
    for (int off = 32; off > 0; off >>= 1) {
        s  += __shfl_xor(s, off);
        sq += __shfl_xor(sq, off);
    }
    __shared__ float ls[4], lq[4];
    __shared__ float mean_s, rstd_s;
    const int wid = tid >> 6, lane = tid & 63;
    if (lane == 0) { ls[wid] = s; lq[wid] = sq; }
    __syncthreads();
    if (tid == 0) {
        float ts = ls[0] + ls[1] + ls[2] + ls[3];
        float tq = lq[0] + lq[1] + lq[2] + lq[3];
        float mean = ts * (1.f / DM);
        float var  = tq * (1.f / DM) - mean * mean;
        mean_s = mean;
        rstd_s = rsqrtf(fmaxf(var, 0.f) + 1e-5f);
    }
    __syncthreads();
    const float mean = mean_s, rstd = rstd_s;
    float4 g = ((const float4*)gamma)[tid];
    float4 b = ((const float4*)beta)[tid];
    float o[4];
    o[0] = (v.x - mean) * rstd * g.x + b.x;
    o[1] = (v.y - mean) * rstd * g.y + b.y;
    o[2] = (v.z - mean) * rstd * g.z + b.z;
    o[3] = (v.w - mean) * rstd * g.w + b.w;
    short4 hv, lv;
    split_bf16(o[0], hv.x, lv.x);
    split_bf16(o[1], hv.y, lv.y);
    split_bf16(o[2], hv.z, lv.z);
    split_bf16(o[3], hv.w, lv.w);
    short* rowp = A2 + (size_t)row * KP;
    *(short4*)(rowp + 4 * tid)        = hv;
    *(short4*)(rowp + 1024 + 4 * tid) = lv;
}

// ---------------- 2a. W -> Bt (transpose + bf16 hi|lo) ----------------
__global__ __launch_bounds__(256) void wprep_kernel(const float* __restrict__ W,
                                                    short* __restrict__ Bt) {
    __shared__ float T[32][33];
    const int k0 = blockIdx.x * 32, j0 = blockIdx.y * 32;
    const int t = threadIdx.x;
    const int r = t >> 3, c4 = (t & 7) * 4;
    float4 v = *(const float4*)(W + (size_t)(k0 + r) * NJ + j0 + c4);
    T[r][c4 + 0] = v.x; T[r][c4 + 1] = v.y; T[r][c4 + 2] = v.z; T[r][c4 + 3] = v.w;
    __syncthreads();
    const int jr = r, kc = c4;
    short4 hv, lv;
    split_bf16(T[kc + 0][jr], hv.x, lv.x);
    split_bf16(T[kc + 1][jr], hv.y, lv.y);
    split_bf16(T[kc + 2][jr], hv.z, lv.z);
    split_bf16(T[kc + 3][jr], hv.w, lv.w);
    short* rowp = Bt + (size_t)(j0 + jr) * KP;
    *(short4*)(rowp + k0 + kc)        = hv;
    *(short4*)(rowp + 1024 + k0 + kc) = lv;
}

// ---------------- 2b. MFMA GEMM: pt[j,s] = ((xn @ W)^T + b) ----------------
// 64(s) x 64(j) tile, BK=64, 48 K-iters = 3 segments (xh*wh, xh*wl, xl*wh) x 16.
// Grid 64(s, fast) x 14(j) = 896 blocks ~ 3.5 blocks/CU. LDS 32 KB (2 x 16 KB
// dbuf), prefetch issued right after the barrier. Wave = 32x32 microtile.
__global__ __launch_bounds__(256) void gemm_kernel(const short* __restrict__ A2,
                                                   const short* __restrict__ Bt,
                                                   const float* __restrict__ bias,
                                                   float* __restrict__ pt) {
    __shared__ short As[2][4096];   // 4 m-tiles x 2 k-slots x 512 shorts
    __shared__ short Bs[2][4096];
    const int tid = threadIdx.x;
    const int l = tid & 63, w = tid >> 6;
    const int s0 = blockIdx.x * 64;
    const int j0 = blockIdx.y * 64;
    const int lm = l & 15;          // row within 16-row tile
    const int lc8 = (l >> 4) * 8;   // k-chunk offset (shorts) within 32-k slot

    const size_t baseA = (size_t)(s0 + w * 16 + lm) * KP + lc8;
    const size_t baseB = (size_t)(j0 + w * 16 + lm) * KP + lc8;

    f32x4 acc[2][2] = {};

    auto stage = [&](int buf, int kt) {
        const int seg = kt >> 4;
        const int ko  = (kt & 15) << 6;                  // k offset (shorts)
        const int offa = ko + ((seg == 2) ? 1024 : 0);   // xl for seg2
        const int offb = ko + ((seg == 1) ? 1024 : 0);   // wl for seg1
        const short* ga = A2 + baseA + offa;
        const short* gb = Bt + baseB + offb;
        short* la = &As[buf][w * 1024];
        short* lb = &Bs[buf][w * 1024];
        async16(ga,      la);
        async16(ga + 32, la + 512);
        async16(gb,      lb);
        async16(gb + 32, lb + 512);
    };

    const short* fAb = &As[0][(w & 1) * 2048 + l * 8];
    const short* fBb = &Bs[0][(w >> 1) * 2048 + l * 8];

    stage(0, 0);
    for (int kt = 0; kt < 48; ++kt) {
        const int cur = kt & 1;
        __syncthreads();                      // drains cur's loads; prior compute done
        if (kt + 1 < 48) stage(cur ^ 1, kt + 1);
        const short* fA = fAb + cur * 4096;
        const short* fB = fBb + cur * 4096;
        bf16x8 a[2][2], b[2][2];
        #pragma unroll
        for (int mi = 0; mi < 2; ++mi) {
            a[mi][0] = *(const bf16x8*)(fA + mi * 1024);
            a[mi][1] = *(const bf16x8*)(fA + mi * 1024 + 512);
        }
        #pragma unroll
        for (int ni = 0; ni < 2; ++ni) {
            b[ni][0] = *(const bf16x8*)(fB + ni * 1024);
            b[ni][1] = *(const bf16x8*)(fB + ni * 1024 + 512);
        }
        #pragma unroll
        for (int mi = 0; mi < 2; ++mi)
            #pragma unroll
            for (int ni = 0; ni < 2; ++ni) {
                acc[mi][ni] = __builtin_amdgcn_mfma_f32_16x16x32_bf16(
                    a[mi][0], b[ni][0], acc[mi][ni], 0, 0, 0);
                acc[mi][ni] = __builtin_amdgcn_mfma_f32_16x16x32_bf16(
                    a[mi][1], b[ni][1], acc[mi][ni], 0, 0, 0);
            }
    }

    // epilogue: C/D layout col=lane&15 (j-within-tile), row=(lane>>4)*4+reg (s)
    const int srow = (l >> 4) * 4;
    const int jcol = l & 15;
    #pragma unroll
    for (int ni = 0; ni < 2; ++ni) {
        const int j = j0 + ((w >> 1) * 2 + ni) * 16 + jcol;
        if (j < NJ) {
            const float bj = bias[j];
            #pragma unroll
            for (int mi = 0; mi < 2; ++mi) {
                f32x4 v = acc[mi][ni];
                v[0] += bj; v[1] += bj; v[2] += bj; v[3] += bj;
                *(f32x4*)(pt + (size_t)j * SEQ + s0 + ((w & 1) * 2 + mi) * 16 + srow) = v;
            }
        }
    }
}

// ---------------- 3. Spring recurrence + per-wave LDS window scatter ----------------
// Stride-64 t-schedule: 5 chains at t = q, q+64, ..., q+256 (chain c advanced by rot
// each q; chains pre-jumped by rot^64). Wave-private 364-float LDS window, plain RMW
// at win[lane + q + 64c].
// R5 FAILURE: lane l's read at step q aliases lane l+1's write at step q-1 — a
// cross-lane RAW the compiler cannot see (per-thread addresses differ), so it
// reordered the non-volatile ds ops and dropped accumulations (absmax 7.57).
// FIX: all window accesses VOLATILE -> strict program order; the per-wave in-order
// DS pipe then guarantees cross-lane visibility (all step q-1 writes precede all
// step q reads). Reads batched 5-wide before writes to amortize ds_read latency.
__global__ __launch_bounds__(256) void spring_kernel(const float* __restrict__ pt,
                                                     float* __restrict__ kin) {
    __shared__ float wins[4][368];
    const int tid  = threadIdx.x;
    const int lane = tid & 63;
    const int wid  = tid >> 6;
    const int s0   = blockIdx.x * 256;
    const int imu  = blockIdx.y;
    const int sbase = s0 + (wid << 6);
    const int s    = sbase + lane;
    volatile float* win = &wins[wid][0];

    // zero the wave-private window (volatile, in-order with later RMWs)
    #pragma unroll
    for (int r = 0; r < 6; ++r) {
        int idx = r * 64 + lane;
        if (idx < 368) win[idx] = 0.f;
    }

    const int base = imu * SEQ + s;
    const float p0  = pt[(size_t)0 * PLANE + base];
    const float p1  = pt[(size_t)1 * PLANE + base];
    const float p2  = pt[(size_t)2 * PLANE + base];
    const float p3  = pt[(size_t)3 * PLANE + base];
    const float c1  = pt[(size_t)4 * PLANE + base];
    const float c2  = pt[(size_t)5 * PLANE + base];
    const float ph1 = pt[(size_t)6 * PLANE + base];
    const float ph2 = pt[(size_t)7 * PLANE + base];

    float dd = softplus_f(p1);
    float kk = dd * dd * 0.25f + softplus_f(p0);
    float om1 = 0.5f * sqrtf(fmaxf(4.f * kk - dd * dd, 0.f));
    float dt = softplus_f(p3);
    float kt = dt * dt * 0.25f + softplus_f(p2);
    float om2 = 0.5f * sqrtf(fmaxf(4.f * kt - dt * dt, 0.f));
    float e1 = expf(-0.5f * dd), e2 = expf(-0.5f * dt);
    float sn, cs;
    sincosf(om1, &sn, &cs); const float R1r = e1 * cs, R1i = e1 * sn;
    sincosf(om2, &sn, &cs); const float R2r = e2 * cs, R2i = e2 * sn;

    // rot^64 via 6 squarings
    float q1r = R1r, q1i = R1i, q2r = R2r, q2i = R2i;
    #pragma unroll
    for (int i = 0; i < 6; ++i) {
        float nr = q1r * q1r - q1i * q1i; q1i = 2.f * q1r * q1i; q1r = nr;
        nr = q2r * q2r - q2i * q2i;       q2i = 2.f * q2r * q2i; q2r = nr;
    }

    // chain states: st[c] = z * rot^(64c)
    float re1[5], im1[5], re2[5], im2[5];
    sincosf(ph1, &sn, &cs); im1[0] = c1 * sn; re1[0] = c1 * cs;
    sincosf(ph2, &sn, &cs); im2[0] = c2 * sn; re2[0] = c2 * cs;
    #pragma unroll
    for (int c = 1; c < 5; ++c) {
        re1[c] = re1[c-1] * q1r - im1[c-1] * q1i;
        im1[c] = re1[c-1] * q1i + im1[c-1] * q1r;
        re2[c] = re2[c-1] * q2r - im2[c-1] * q2i;
        im2[c] = re2[c-1] * q2i + im2[c-1] * q2r;
    }

    #define ADVANCE(c)                                           \
        {                                                        \
            float nr1 = fmaf(re1[c], R1r, -im1[c] * R1i);        \
            im1[c] = fmaf(re1[c], R1i, im1[c] * R1r);            \
            re1[c] = nr1;                                        \
            float nr2 = fmaf(re2[c], R2r, -im2[c] * R2i);        \
            im2[c] = fmaf(re2[c], R2i, im2[c] * R2r);            \
            re2[c] = nr2;                                        \
        }

    for (int q = 0; q < 44; ++q) {       // chains 0..4: t = q, q+64, .., q+256
        float wv[5];
        #pragma unroll
        for (int c = 0; c < 5; ++c) wv[c] = win[lane + q + c * 64];
        #pragma unroll
        for (int c = 0; c < 5; ++c) win[lane + q + c * 64] = wv[c] + im1[c] + im2[c];
        ADVANCE(0) ADVANCE(1) ADVANCE(2) ADVANCE(3) ADVANCE(4)
    }
    for (int q = 44; q < 64; ++q) {      // chain 4 would exceed t=299
        float wv[4];
        #pragma unroll
        for (int c = 0; c < 4; ++c) wv[c] = win[lane + q + c * 64];
        #pragma unroll
        for (int c = 0; c < 4; ++c) win[lane + q + c * 64] = wv[c] + im1[c] + im2[c];
        ADVANCE(0) ADVANCE(1) ADVANCE(2) ADVANCE(3)
    }
    #undef ADVANCE

    // flush wave window; positions >= SEQ dropped (matches reference mask)
    #pragma unroll
    for (int r = 0; r < 6; ++r) {
        int idx = r * 64 + lane;
        if (idx < 364) {
            int pos = sbase + idx;
            if (pos < SEQ) {
                __hip_atomic_fetch_add(&kin[(size_t)imu * SEQ + pos], win[idx],
                                       __ATOMIC_RELAXED, __HIP_MEMORY_SCOPE_AGENT);
            }
        }
    }
}

// ---------------- 4. acc/gyro base & std outputs ----------------
__global__ __launch_bounds__(256) void tail_kernel(const float* __restrict__ pt,
                                                   float* __restrict__ out) {
    int idx = blockIdx.x * 256 + threadIdx.x;
    if (idx >= 4 * PLANE) return;
    float v = pt[(size_t)8 * PLANE + idx];
    int q = idx / PLANE;
    if (q & 1) v = softplus_f(v);
    out[(size_t)PLANE + idx] = v;
}

extern "C" void kernel_launch(void* const* d_in, const int* in_sizes, int n_in,
                              void* d_out, int out_size, void* d_ws, size_t ws_size,
                              hipStream_t stream) {
    const float* hs    = (const float*)d_in[0];
    const float* gamma = (const float*)d_in[1];
    const float* beta  = (const float*)d_in[2];
    const float* W     = (const float*)d_in[3];
    const float* b     = (const float*)d_in[4];
    float* out = (float*)d_out;

    short* A2 = (short*)d_ws;                         // 4096*2048 bf16
    short* Bt = A2 + (size_t)SEQ * KP;                // 864*2048 bf16
    float* pt = (float*)(Bt + (size_t)NJ * KP);       // 864*4096 f32

    hipMemsetAsync(out, 0, (size_t)PLANE * sizeof(float), stream);

    wprep_kernel<<<dim3(DM / 32, NJ / 32), 256, 0, stream>>>(W, Bt);
    ln_kernel<<<SEQ, 256, 0, stream>>>(hs, gamma, beta, A2);
    gemm_kernel<<<dim3(SEQ / 64, 14), 256, 0, stream>>>(A2, Bt, b, pt);
    spring_kernel<<<dim3(SEQ / 256, NIMU), 256, 0, stream>>>(pt, out);
    tail_kernel<<<(4 * PLANE + 255) / 256, 256, 0, stream>>>(pt, out);
}

// Round 7
// 169.208 us; speedup vs baseline: 1.9013x; 1.2635x over previous
//
#include <hip/hip_runtime.h>
#include <hip/hip_bf16.h>
#include <math.h>

// Problem constants
#define SEQ 4096
#define DM  1024
#define NIMU 72
#define NNOISE 12
#define NJ (NIMU*NNOISE)     // 864
#define TSTEPS 300
#define PLANE (NIMU*SEQ)     // 294912

// Fragment-linear layouts (16x16x32 bf16 MFMA operand granules):
//   granule(tile, ch) = 512 shorts; lane l holds 8 shorts at +l*8:
//     row = l&15 (m or n), k = ch*32 + (l>>4)*8 + 0..7
//   ch 0..31 = hi half (k 0..1023), ch 32..63 = lo half.
// A2f : 256 s_tiles x 64 ch x 512 shorts = 16.78 MB
// Btf : 56  j_tiles x 64 ch x 512 shorts =  3.67 MB (j_tiles 54,55 unwritten junk)
// pt  : 864 x 4096 f32 = 14.16 MB
#define A2F_SHORTS ((size_t)256 * 64 * 512)
#define BTF_SHORTS ((size_t)56 * 64 * 512)

typedef __attribute__((ext_vector_type(8))) short bf16x8;
typedef __attribute__((ext_vector_type(4))) float f32x4;

__device__ __forceinline__ float softplus_f(float x) {
    return fmaxf(x, 0.f) + log1pf(expf(-fabsf(x)));
}

// round-to-nearest-even bf16 split: x ~= hi + lo with |err| ~ 2^-16 * |x|
__device__ __forceinline__ void split_bf16(float x, short& hi, short& lo) {
    unsigned b = __float_as_uint(x);
    unsigned h = (b + 0x7FFFu + ((b >> 16) & 1u)) >> 16;
    float hf = __uint_as_float(h << 16);
    float r = x - hf;
    unsigned b2 = __float_as_uint(r);
    unsigned l2 = (b2 + 0x7FFFu + ((b2 >> 16) & 1u)) >> 16;
    hi = (short)h;
    lo = (short)l2;
}

// ---------------- 1. LayerNorm -> A2f (fragment-linear bf16 hi|lo) ----------------
// Block = one s_tile (16 rows). thread: mrow = tid>>4 (0..15), g = tid&15.
// Thread covers k-quads k4 = g*4 + i*64 (i=0..15). Row stats via shfl_xor over g
// (low 4 lane bits). Writes: short4 (8 B) per quad straight into A2f; the 8 lanes
// sharing (ch,c) exactly tile one 64B line, so scattered stores stay line-efficient.
__global__ __launch_bounds__(256) void ln_kernel(const float* __restrict__ x,
                                                 const float* __restrict__ gamma,
                                                 const float* __restrict__ beta,
                                                 short* __restrict__ A2f) {
    const int s_tile = blockIdx.x;
    const int tid = threadIdx.x;
    const int mrow = tid >> 4;      // row within s_tile
    const int g    = tid & 15;
    const int row  = s_tile * 16 + mrow;
    const float4* xr = (const float4*)(x + (size_t)row * DM);

    float s = 0.f, sq = 0.f;
    #pragma unroll
    for (int i = 0; i < 16; ++i) {
        float4 v = xr[g + 16 * i];
        s  += v.x + v.y + v.z + v.w;
        sq += v.x*v.x + v.y*v.y + v.z*v.z + v.w*v.w;
    }
    #pragma unroll
    for (int off = 1; off < 16; off <<= 1) {
        s  += __shfl_xor(s, off);
        sq += __shfl_xor(sq, off);
    }
    const float mean = s * (1.f / DM);
    const float var  = sq * (1.f / DM) - mean * mean;
    const float rstd = rsqrtf(fmaxf(var, 0.f) + 1e-5f);

    #pragma unroll
    for (int i = 0; i < 16; ++i) {
        float4 v = xr[g + 16 * i];
        float4 gm = ((const float4*)gamma)[g + 16 * i];
        float4 bt = ((const float4*)beta)[g + 16 * i];
        float o[4];
        o[0] = (v.x - mean) * rstd * gm.x + bt.x;
        o[1] = (v.y - mean) * rstd * gm.y + bt.y;
        o[2] = (v.z - mean) * rstd * gm.z + bt.z;
        o[3] = (v.w - mean) * rstd * gm.w + bt.w;
        short4 hv, lv;
        split_bf16(o[0], hv.x, lv.x);
        split_bf16(o[1], hv.y, lv.y);
        split_bf16(o[2], hv.z, lv.z);
        split_bf16(o[3], hv.w, lv.w);
        // k4 = g*4 + i*64 -> ch=(g>>3)+2i, c=(g>>1)&3, j0=(g&1)*4
        const int ch = (g >> 3) + 2 * i;
        const size_t base = ((size_t)s_tile * 64 + ch) * 512
                          + mrow * 8 + ((g >> 1) & 3) * 128 + (g & 1) * 4;
        *(short4*)(A2f + base)             = hv;   // hi: ch
        *(short4*)(A2f + base + 32 * 512)  = lv;   // lo: ch+32
    }
}

// ---------------- 2a. W -> Btf (transpose + split, fragment-linear) ----------------
__global__ __launch_bounds__(256) void wprep_kernel(const float* __restrict__ W,
                                                    short* __restrict__ Btf) {
    __shared__ float T[32][33];
    const int k0 = blockIdx.x * 32, j0 = blockIdx.y * 32;
    const int t = threadIdx.x;
    {
        const int r = t >> 3, c4 = (t & 7) * 4;
        float4 v = *(const float4*)(W + (size_t)(k0 + r) * NJ + j0 + c4);
        T[r][c4 + 0] = v.x; T[r][c4 + 1] = v.y; T[r][c4 + 2] = v.z; T[r][c4 + 3] = v.w;
    }
    __syncthreads();
    if (t < 128) {
        const int gq = t >> 6;          // which 16-j group
        const int l  = t & 63;
        const int n = l & 15, c = l >> 4;
        const int jt = blockIdx.y * 2 + gq;       // j_tile
        bf16x8 hv, lv;
        #pragma unroll
        for (int o = 0; o < 8; ++o) {
            short h, lo_;
            split_bf16(T[c * 8 + o][gq * 16 + n], h, lo_);
            hv[o] = h; lv[o] = lo_;
        }
        short* dh = Btf + ((size_t)jt * 64 + blockIdx.x) * 512 + l * 8;
        *(bf16x8*)dh = hv;
        *(bf16x8*)(dh + (size_t)32 * 512) = lv;   // lo chunk = ch+32
    }
}

// ---------------- 2b. Barrier-free MFMA GEMM: pt[j,s] = ((xn @ W)^T + b) ----------------
// NO LDS, NO __syncthreads (R3/R4/R6: global_load_lds+barrier = vmcnt(0) drain every
// iter, ~1800 cyc/iter invariant). Operands pre-swizzled fragment-linear; a/b frags
// loaded with plain coalesced global_load_dwordx4 (wave-uniform base + l*16), compiler
// pipelines with fine vmcnt. Block 128x128 (4 waves x 64x64). 32 K-iters: load
// {ah,al,bh,bl} x4 tiles (16 KB), 48 MFMA (ah*bh + ah*bl + al*bh) -> every granule
// fetched once. Register double-buffer. Grid (32 s fast, 7 j): 7 j-siblings of an
// s-slice land on one XCD -> A fetched ~once from HBM.
__global__ __launch_bounds__(256, 1) void gemm_kernel(const short* __restrict__ A2f,
                                                      const short* __restrict__ Btf,
                                                      const float* __restrict__ bias,
                                                      float* __restrict__ pt) {
    const int l = threadIdx.x & 63, w = threadIdx.x >> 6;
    const int st0 = blockIdx.x * 8 + (w & 1) * 4;    // wave's m-tile base
    const int jt0 = blockIdx.y * 8 + (w >> 1) * 4;   // wave's n-tile base
    const short* aB = A2f + (size_t)st0 * (64 * 512) + l * 8;
    const short* bB = Btf + (size_t)jt0 * (64 * 512) + l * 8;

    f32x4 acc[4][4] = {};
    bf16x8 ah[2][4], al[2][4], bh[2][4], bl[2][4];

    auto ldstep = [&](int slot, int i) {
        #pragma unroll
        for (int t = 0; t < 4; ++t) {
            ah[slot][t] = *(const bf16x8*)(aB + ((size_t)t * 64 + i) * 512);
            al[slot][t] = *(const bf16x8*)(aB + ((size_t)t * 64 + 32 + i) * 512);
            bh[slot][t] = *(const bf16x8*)(bB + ((size_t)t * 64 + i) * 512);
            bl[slot][t] = *(const bf16x8*)(bB + ((size_t)t * 64 + 32 + i) * 512);
        }
    };

    ldstep(0, 0);
    #pragma unroll 2
    for (int i = 0; i < 32; ++i) {
        const int cur = i & 1;
        if (i + 1 < 32) ldstep(cur ^ 1, i + 1);   // loads in flight during MFMA
        #pragma unroll
        for (int mi = 0; mi < 4; ++mi)
            #pragma unroll
            for (int ni = 0; ni < 4; ++ni)
                acc[mi][ni] = __builtin_amdgcn_mfma_f32_16x16x32_bf16(
                    ah[cur][mi], bh[cur][ni], acc[mi][ni], 0, 0, 0);
        #pragma unroll
        for (int mi = 0; mi < 4; ++mi)
            #pragma unroll
            for (int ni = 0; ni < 4; ++ni)
                acc[mi][ni] = __builtin_amdgcn_mfma_f32_16x16x32_bf16(
                    ah[cur][mi], bl[cur][ni], acc[mi][ni], 0, 0, 0);
        #pragma unroll
        for (int mi = 0; mi < 4; ++mi)
            #pragma unroll
            for (int ni = 0; ni < 4; ++ni)
                acc[mi][ni] = __builtin_amdgcn_mfma_f32_16x16x32_bf16(
                    al[cur][mi], bh[cur][ni], acc[mi][ni], 0, 0, 0);
    }

    // epilogue: C/D layout col=lane&15 (j-within-tile), row=(lane>>4)*4+reg (s)
    const int srow = (l >> 4) * 4;
    const int jcol = l & 15;
    #pragma unroll
    for (int ni = 0; ni < 4; ++ni) {
        const int j = (jt0 + ni) * 16 + jcol;
        if (j < NJ) {
            const float bj = bias[j];
            #pragma unroll
            for (int mi = 0; mi < 4; ++mi) {
                f32x4 v = acc[mi][ni];
                v[0] += bj; v[1] += bj; v[2] += bj; v[3] += bj;
                *(f32x4*)(pt + (size_t)j * SEQ + (st0 + mi) * 16 + srow) = v;
            }
        }
    }
}

// ---------------- 3. Spring recurrence + register diagonal scatter ----------------
// R4-verified shfl scheme, but each 4-batch hoisted: 4 recurrence advances first
// (snapshot v[i]), then 4 independent shfls in flight, then 4 predicated adds —
// breaks the serialized advance->shfl->add chain.
__global__ __launch_bounds__(256) void spring_kernel(const float* __restrict__ pt,
                                                     float* __restrict__ kin) {
    const int tid  = threadIdx.x;
    const int lane = tid & 63;
    const int wid  = tid >> 6;
    const int s0   = blockIdx.x * 256;
    const int imu  = blockIdx.y;
    const int sbase = s0 + (wid << 6);
    const int s    = sbase + lane;

    const int base = imu * SEQ + s;
    const float p0  = pt[(size_t)0 * PLANE + base];
    const float p1  = pt[(size_t)1 * PLANE + base];
    const float p2  = pt[(size_t)2 * PLANE + base];
    const float p3  = pt[(size_t)3 * PLANE + base];
    const float c1  = pt[(size_t)4 * PLANE + base];
    const float c2  = pt[(size_t)5 * PLANE + base];
    const float ph1 = pt[(size_t)6 * PLANE + base];
    const float ph2 = pt[(size_t)7 * PLANE + base];

    float dd = softplus_f(p1);
    float kk = dd * dd * 0.25f + softplus_f(p0);
    float om1 = 0.5f * sqrtf(fmaxf(4.f * kk - dd * dd, 0.f));
    float dt = softplus_f(p3);
    float kt = dt * dt * 0.25f + softplus_f(p2);
    float om2 = 0.5f * sqrtf(fmaxf(4.f * kt - dt * dt, 0.f));
    float e1 = expf(-0.5f * dd), e2 = expf(-0.5f * dt);
    float sn, cs;
    sincosf(om1, &sn, &cs); const float mr1 = e1 * cs, mi1 = e1 * sn;
    sincosf(om2, &sn, &cs); const float mr2 = e2 * cs, mi2 = e2 * sn;
    sincosf(ph1, &sn, &cs); float im1 = c1 * sn, re1 = c1 * cs;
    sincosf(ph2, &sn, &cs); float im2 = c2 * sn, re2 = c2 * cs;

    float A[6];
    #pragma unroll
    for (int r = 0; r < 6; ++r) A[r] = 0.f;

    const bool full = (sbase + 64 + TSTEPS <= SEQ);   // wave-uniform

    if (full) {
        #pragma unroll
        for (int tq = 0; tq < 5; ++tq) {
            const int trmax = (tq == 4) ? 44 : 64;   // 300 = 4*64 + 44; both %4==0
            for (int tr0 = 0; tr0 < trmax; tr0 += 4) {
                float v[4], u[4];
                #pragma unroll
                for (int i = 0; i < 4; ++i) {
                    v[i] = im1 + im2;
                    float r1 = fmaf(re1, mr1, -im1 * mi1);
                    im1 = fmaf(re1, mi1, im1 * mr1);
                    re1 = r1;
                    float r2 = fmaf(re2, mr2, -im2 * mi2);
                    im2 = fmaf(re2, mi2, im2 * mr2);
                    re2 = r2;
                }
                #pragma unroll
                for (int i = 0; i < 4; ++i)
                    u[i] = __shfl(v[i], (lane - (tr0 + i)) & 63);
                #pragma unroll
                for (int i = 0; i < 4; ++i) {
                    const int tr = tr0 + i;
                    A[tq]     += (lane >= tr) ? u[i] : 0.f;
                    A[tq + 1] += (lane <  tr) ? u[i] : 0.f;
                }
            }
        }
    } else {
        const int tmax_wave = min(TSTEPS, SEQ - sbase);
        const int tmax_lane = SEQ - s;
        #pragma unroll
        for (int tq = 0; tq < 5; ++tq) {
            const int trmax = min(64, tmax_wave - tq * 64);
            for (int tr = 0; tr < trmax; ++tr) {
                const int t = tq * 64 + tr;
                float val = (t < tmax_lane) ? (im1 + im2) : 0.f;
                float u = __shfl(val, (lane - tr) & 63);
                A[tq]     += (lane >= tr) ? u : 0.f;
                A[tq + 1] += (lane <  tr) ? u : 0.f;
                float r1 = fmaf(re1, mr1, -im1 * mi1);
                im1 = fmaf(re1, mi1, im1 * mr1);
                re1 = r1;
                float r2 = fmaf(re2, mr2, -im2 * mi2);
                im2 = fmaf(re2, mi2, im2 * mr2);
                re2 = r2;
            }
            if (trmax < 64) break;
        }
    }

    #pragma unroll
    for (int r = 0; r < 6; ++r) {
        int pos = sbase + 64 * r + lane;
        if (pos < SEQ) {
            __hip_atomic_fetch_add(&kin[(size_t)imu * SEQ + pos], A[r],
                                   __ATOMIC_RELAXED, __HIP_MEMORY_SCOPE_AGENT);
        }
    }
}

// ---------------- 4. acc/gyro base & std outputs ----------------
__global__ __launch_bounds__(256) void tail_kernel(const float* __restrict__ pt,
                                                   float* __restrict__ out) {
    int idx = blockIdx.x * 256 + threadIdx.x;
    if (idx >= 4 * PLANE) return;
    float v = pt[(size_t)8 * PLANE + idx];
    int q = idx / PLANE;
    if (q & 1) v = softplus_f(v);
    out[(size_t)PLANE + idx] = v;
}

extern "C" void kernel_launch(void* const* d_in, const int* in_sizes, int n_in,
                              void* d_out, int out_size, void* d_ws, size_t ws_size,
                              hipStream_t stream) {
    const float* hs    = (const float*)d_in[0];
    const float* gamma = (const float*)d_in[1];
    const float* beta  = (const float*)d_in[2];
    const float* W     = (const float*)d_in[3];
    const float* b     = (const float*)d_in[4];
    float* out = (float*)d_out;

    short* A2f = (short*)d_ws;                        // 16.78 MB
    short* Btf = A2f + A2F_SHORTS;                    //  3.67 MB
    float* pt  = (float*)(Btf + BTF_SHORTS);          // 14.16 MB

    hipMemsetAsync(out, 0, (size_t)PLANE * sizeof(float), stream);

    ln_kernel<<<SEQ / 16, 256, 0, stream>>>(hs, gamma, beta, A2f);
    wprep_kernel<<<dim3(DM / 32, NJ / 32), 256, 0, stream>>>(W, Btf);
    gemm_kernel<<<dim3(SEQ / 128, 7), 256, 0, stream>>>(A2f, Btf, b, pt);
    spring_kernel<<<dim3(SEQ / 256, NIMU), 256, 0, stream>>>(pt, out);
    tail_kernel<<<(4 * PLANE + 255) / 256, 256, 0, stream>>>(pt, out);
}

// Round 8
// 159.818 us; speedup vs baseline: 2.0130x; 1.0588x over previous
//
#include <hip/hip_runtime.h>
#include <hip/hip_bf16.h>
#include <math.h>

// Problem constants
#define SEQ 4096
#define DM  1024
#define NIMU 72
#define NNOISE 12
#define NJ (NIMU*NNOISE)     // 864
#define TSTEPS 300
#define PLANE (NIMU*SEQ)     // 294912

// Fragment-linear layouts (16x16x32 bf16 MFMA operand granules):
//   granule(tile, ch) = 512 shorts; lane l holds 8 shorts at +l*8:
//     row = l&15 (m or n), k = ch*32 + (l>>4)*8 + 0..7
//   ch 0..31 = hi half (k 0..1023), ch 32..63 = lo half.
// A2f : 256 s_tiles x 64 ch x 512 shorts = 16.78 MB
// Btf : 56  j_tiles x 64 ch x 512 shorts =  3.67 MB (j_tiles 54,55 unwritten junk)
// pt  : 864 x 4096 f32 = 14.16 MB
#define A2F_SHORTS ((size_t)256 * 64 * 512)
#define BTF_SHORTS ((size_t)56 * 64 * 512)

typedef __attribute__((ext_vector_type(8))) short bf16x8;
typedef __attribute__((ext_vector_type(4))) float f32x4;
typedef __attribute__((ext_vector_type(2))) float f32x2;

__device__ __forceinline__ float softplus_f(float x) {
    return fmaxf(x, 0.f) + log1pf(expf(-fabsf(x)));
}

// round-to-nearest-even bf16 split: x ~= hi + lo with |err| ~ 2^-16 * |x|
__device__ __forceinline__ void split_bf16(float x, short& hi, short& lo) {
    unsigned b = __float_as_uint(x);
    unsigned h = (b + 0x7FFFu + ((b >> 16) & 1u)) >> 16;
    float hf = __uint_as_float(h << 16);
    float r = x - hf;
    unsigned b2 = __float_as_uint(r);
    unsigned l2 = (b2 + 0x7FFFu + ((b2 >> 16) & 1u)) >> 16;
    hi = (short)h;
    lo = (short)l2;
}

// ---------------- 1. LayerNorm -> A2f (fragment-linear bf16 hi|lo) ----------------
__global__ __launch_bounds__(256) void ln_kernel(const float* __restrict__ x,
                                                 const float* __restrict__ gamma,
                                                 const float* __restrict__ beta,
                                                 short* __restrict__ A2f) {
    const int s_tile = blockIdx.x;
    const int tid = threadIdx.x;
    const int mrow = tid >> 4;      // row within s_tile
    const int g    = tid & 15;
    const int row  = s_tile * 16 + mrow;
    const float4* xr = (const float4*)(x + (size_t)row * DM);

    float s = 0.f, sq = 0.f;
    #pragma unroll
    for (int i = 0; i < 16; ++i) {
        float4 v = xr[g + 16 * i];
        s  += v.x + v.y + v.z + v.w;
        sq += v.x*v.x + v.y*v.y + v.z*v.z + v.w*v.w;
    }
    #pragma unroll
    for (int off = 1; off < 16; off <<= 1) {
        s  += __shfl_xor(s, off);
        sq += __shfl_xor(sq, off);
    }
    const float mean = s * (1.f / DM);
    const float var  = sq * (1.f / DM) - mean * mean;
    const float rstd = rsqrtf(fmaxf(var, 0.f) + 1e-5f);

    #pragma unroll
    for (int i = 0; i < 16; ++i) {
        float4 v = xr[g + 16 * i];
        float4 gm = ((const float4*)gamma)[g + 16 * i];
        float4 bt = ((const float4*)beta)[g + 16 * i];
        float o[4];
        o[0] = (v.x - mean) * rstd * gm.x + bt.x;
        o[1] = (v.y - mean) * rstd * gm.y + bt.y;
        o[2] = (v.z - mean) * rstd * gm.z + bt.z;
        o[3] = (v.w - mean) * rstd * gm.w + bt.w;
        short4 hv, lv;
        split_bf16(o[0], hv.x, lv.x);
        split_bf16(o[1], hv.y, lv.y);
        split_bf16(o[2], hv.z, lv.z);
        split_bf16(o[3], hv.w, lv.w);
        const int ch = (g >> 3) + 2 * i;
        const size_t base = ((size_t)s_tile * 64 + ch) * 512
                          + mrow * 8 + ((g >> 1) & 3) * 128 + (g & 1) * 4;
        *(short4*)(A2f + base)             = hv;   // hi: ch
        *(short4*)(A2f + base + 32 * 512)  = lv;   // lo: ch+32
    }
}

// ---------------- 2a. W -> Btf (transpose + split, fragment-linear) ----------------
__global__ __launch_bounds__(256) void wprep_kernel(const float* __restrict__ W,
                                                    short* __restrict__ Btf) {
    __shared__ float T[32][33];
    const int k0 = blockIdx.x * 32, j0 = blockIdx.y * 32;
    const int t = threadIdx.x;
    {
        const int r = t >> 3, c4 = (t & 7) * 4;
        float4 v = *(const float4*)(W + (size_t)(k0 + r) * NJ + j0 + c4);
        T[r][c4 + 0] = v.x; T[r][c4 + 1] = v.y; T[r][c4 + 2] = v.z; T[r][c4 + 3] = v.w;
    }
    __syncthreads();
    if (t < 128) {
        const int gq = t >> 6;          // which 16-j group
        const int l  = t & 63;
        const int n = l & 15, c = l >> 4;
        const int jt = blockIdx.y * 2 + gq;       // j_tile
        bf16x8 hv, lv;
        #pragma unroll
        for (int o = 0; o < 8; ++o) {
            short h, lo_;
            split_bf16(T[c * 8 + o][gq * 16 + n], h, lo_);
            hv[o] = h; lv[o] = lo_;
        }
        short* dh = Btf + ((size_t)jt * 64 + blockIdx.x) * 512 + l * 8;
        *(bf16x8*)dh = hv;
        *(bf16x8*)(dh + (size_t)32 * 512) = lv;   // lo chunk = ch+32
    }
}

// ---------------- 2b. Barrier-free MFMA GEMM: pt[j,s] = ((xn @ W)^T + b) ----------------
__global__ __launch_bounds__(256, 1) void gemm_kernel(const short* __restrict__ A2f,
                                                      const short* __restrict__ Btf,
                                                      const float* __restrict__ bias,
                                                      float* __restrict__ pt) {
    const int l = threadIdx.x & 63, w = threadIdx.x >> 6;
    const int st0 = blockIdx.x * 8 + (w & 1) * 4;    // wave's m-tile base
    const int jt0 = blockIdx.y * 8 + (w >> 1) * 4;   // wave's n-tile base
    const short* aB = A2f + (size_t)st0 * (64 * 512) + l * 8;
    const short* bB = Btf + (size_t)jt0 * (64 * 512) + l * 8;

    f32x4 acc[4][4] = {};
    bf16x8 ah[2][4], al[2][4], bh[2][4], bl[2][4];

    auto ldstep = [&](int slot, int i) {
        #pragma unroll
        for (int t = 0; t < 4; ++t) {
            ah[slot][t] = *(const bf16x8*)(aB + ((size_t)t * 64 + i) * 512);
            al[slot][t] = *(const bf16x8*)(aB + ((size_t)t * 64 + 32 + i) * 512);
            bh[slot][t] = *(const bf16x8*)(bB + ((size_t)t * 64 + i) * 512);
            bl[slot][t] = *(const bf16x8*)(bB + ((size_t)t * 64 + 32 + i) * 512);
        }
    };

    ldstep(0, 0);
    #pragma unroll 2
    for (int i = 0; i < 32; ++i) {
        const int cur = i & 1;
        if (i + 1 < 32) ldstep(cur ^ 1, i + 1);   // loads in flight during MFMA
        #pragma unroll
        for (int mi = 0; mi < 4; ++mi)
            #pragma unroll
            for (int ni = 0; ni < 4; ++ni)
                acc[mi][ni] = __builtin_amdgcn_mfma_f32_16x16x32_bf16(
                    ah[cur][mi], bh[cur][ni], acc[mi][ni], 0, 0, 0);
        #pragma unroll
        for (int mi = 0; mi < 4; ++mi)
            #pragma unroll
            for (int ni = 0; ni < 4; ++ni)
                acc[mi][ni] = __builtin_amdgcn_mfma_f32_16x16x32_bf16(
                    ah[cur][mi], bl[cur][ni], acc[mi][ni], 0, 0, 0);
        #pragma unroll
        for (int mi = 0; mi < 4; ++mi)
            #pragma unroll
            for (int ni = 0; ni < 4; ++ni)
                acc[mi][ni] = __builtin_amdgcn_mfma_f32_16x16x32_bf16(
                    al[cur][mi], bh[cur][ni], acc[mi][ni], 0, 0, 0);
    }

    // epilogue: C/D layout col=lane&15 (j-within-tile), row=(lane>>4)*4+reg (s)
    const int srow = (l >> 4) * 4;
    const int jcol = l & 15;
    #pragma unroll
    for (int ni = 0; ni < 4; ++ni) {
        const int j = (jt0 + ni) * 16 + jcol;
        if (j < NJ) {
            const float bj = bias[j];
            #pragma unroll
            for (int mi = 0; mi < 4; ++mi) {
                f32x4 v = acc[mi][ni];
                v[0] += bj; v[1] += bj; v[2] += bj; v[3] += bj;
                *(f32x4*)(pt + (size_t)j * SEQ + (st0 + mi) * 16 + srow) = v;
            }
        }
    }
}

// ---------------- 3. Spring recurrence + register diagonal scatter ----------------
// R7: 54us @ VALUBusy 59% — serial 300-step chain, scalar osc math, 4.5 waves/SIMD.
// R8 changes: (a) both oscillators packed in float2 -> v_pk_fma_f32 halves advance
// VALU; (b) t-split x2 via blockIdx.z: half 0 = t in [0,152), half 1 = [152,300)
// (both tail chunks %4==0). Half 1 starts from z*R^152 (exp-by-squaring, 8 sq —
// fewer rounding steps than 152 sequential muls). Window = 4 accumulator regs
// (64+152 <= 256). Waves double: 9216 -> 9/SIMD hides the dependent-chain latency.
__global__ __launch_bounds__(256) void spring_kernel(const float* __restrict__ pt,
                                                     float* __restrict__ kin) {
    const int tid  = threadIdx.x;
    const int lane = tid & 63;
    const int wid  = tid >> 6;
    const int s0   = blockIdx.x * 256;
    const int imu  = blockIdx.y;
    const int th   = blockIdx.z;             // t-half
    const int tbeg = th ? 152 : 0;
    const int tlen = th ? 148 : 152;
    const int sbase = s0 + (wid << 6);
    const int s    = sbase + lane;

    const int base = imu * SEQ + s;
    const float p0  = pt[(size_t)0 * PLANE + base];
    const float p1  = pt[(size_t)1 * PLANE + base];
    const float p2  = pt[(size_t)2 * PLANE + base];
    const float p3  = pt[(size_t)3 * PLANE + base];
    const float c1  = pt[(size_t)4 * PLANE + base];
    const float c2  = pt[(size_t)5 * PLANE + base];
    const float ph1 = pt[(size_t)6 * PLANE + base];
    const float ph2 = pt[(size_t)7 * PLANE + base];

    float dd = softplus_f(p1);
    float kk = dd * dd * 0.25f + softplus_f(p0);
    float om1 = 0.5f * sqrtf(fmaxf(4.f * kk - dd * dd, 0.f));
    float dt = softplus_f(p3);
    float kt = dt * dt * 0.25f + softplus_f(p2);
    float om2 = 0.5f * sqrtf(fmaxf(4.f * kt - dt * dt, 0.f));
    float e1 = expf(-0.5f * dd), e2 = expf(-0.5f * dt);
    float sn, cs, sn2, cs2;
    sincosf(om1, &sn, &cs);
    sincosf(om2, &sn2, &cs2);
    f32x2 Rr = {e1 * cs, e2 * cs2};          // per-step rotation (packed: osc1, osc2)
    f32x2 Ri = {e1 * sn, e2 * sn2};
    sincosf(ph1, &sn, &cs);
    sincosf(ph2, &sn2, &cs2);
    f32x2 zr = {c1 * cs, c2 * cs2};          // state (packed)
    f32x2 zi = {c1 * sn, c2 * sn2};

    if (th) {
        // z *= R^152 (exp-by-squaring; 152 = 0b10011000)
        f32x2 prr = Rr, pri = Ri;
        f32x2 qr = {1.f, 1.f}, qi = {0.f, 0.f};
        int e = 152;
        while (e) {
            if (e & 1) {
                f32x2 nr = qr * prr - qi * pri;
                qi = qr * pri + qi * prr;
                qr = nr;
            }
            f32x2 nr = prr * prr - pri * pri;
            pri = 2.f * prr * pri;
            prr = nr;
            e >>= 1;
        }
        f32x2 nr = zr * qr - zi * qi;
        zi = zr * qi + zi * qr;
        zr = nr;
    }

    float A[4];
    #pragma unroll
    for (int r = 0; r < 4; ++r) A[r] = 0.f;

    // wave-uniform fast-path condition: every (lane, t') contribution is in-range
    const bool full = (sbase + 63 + tbeg + tlen - 1) < SEQ;

    if (full) {
        #pragma unroll
        for (int tq = 0; tq < 3; ++tq) {
            const int trmax = (tq == 2) ? (tlen - 128) : 64;   // 64,64,{24|20}
            for (int tr0 = 0; tr0 < trmax; tr0 += 4) {
                float v[4], u[4];
                #pragma unroll
                for (int i = 0; i < 4; ++i) {
                    v[i] = zi.x + zi.y;
                    f32x2 nr = zr * Rr - zi * Ri;
                    zi = zr * Ri + zi * Rr;
                    zr = nr;
                }
                #pragma unroll
                for (int i = 0; i < 4; ++i)
                    u[i] = __shfl(v[i], (lane - (tr0 + i)) & 63);
                #pragma unroll
                for (int i = 0; i < 4; ++i) {
                    const int tr = tr0 + i;
                    A[tq]     += (lane >= tr) ? u[i] : 0.f;
                    A[tq + 1] += (lane <  tr) ? u[i] : 0.f;
                }
            }
        }
    } else {
        const int tmax_lane = SEQ - s - tbeg;    // valid t' < this (may be <=0)
        #pragma unroll
        for (int tq = 0; tq < 3; ++tq) {
            const int trmax = (tq == 2) ? (tlen - 128) : 64;
            for (int tr = 0; tr < trmax; ++tr) {
                const int t2 = tq * 64 + tr;
                float val = (t2 < tmax_lane) ? (zi.x + zi.y) : 0.f;
                float u = __shfl(val, (lane - tr) & 63);
                A[tq]     += (lane >= tr) ? u : 0.f;
                A[tq + 1] += (lane <  tr) ? u : 0.f;
                f32x2 nr = zr * Rr - zi * Ri;
                zi = zr * Ri + zi * Rr;
                zr = nr;
            }
        }
    }

    // flush: A[r] holds position pbase + 64r + lane, valid idx < tlen+63
    const int pbase = sbase + tbeg;
    #pragma unroll
    for (int r = 0; r < 4; ++r) {
        const int idx = r * 64 + lane;
        if (idx < tlen + 63) {
            const int pos = pbase + idx;
            if (pos < SEQ) {
                __hip_atomic_fetch_add(&kin[(size_t)imu * SEQ + pos], A[r],
                                       __ATOMIC_RELAXED, __HIP_MEMORY_SCOPE_AGENT);
            }
        }
    }
}

// ---------------- 4. acc/gyro base & std outputs ----------------
__global__ __launch_bounds__(256) void tail_kernel(const float* __restrict__ pt,
                                                   float* __restrict__ out) {
    int idx = blockIdx.x * 256 + threadIdx.x;
    if (idx >= 4 * PLANE) return;
    float v = pt[(size_t)8 * PLANE + idx];
    int q = idx / PLANE;
    if (q & 1) v = softplus_f(v);
    out[(size_t)PLANE + idx] = v;
}

extern "C" void kernel_launch(void* const* d_in, const int* in_sizes, int n_in,
                              void* d_out, int out_size, void* d_ws, size_t ws_size,
                              hipStream_t stream) {
    const float* hs    = (const float*)d_in[0];
    const float* gamma = (const float*)d_in[1];
    const float* beta  = (const float*)d_in[2];
    const float* W     = (const float*)d_in[3];
    const float* b     = (const float*)d_in[4];
    float* out = (float*)d_out;

    short* A2f = (short*)d_ws;                        // 16.78 MB
    short* Btf = A2f + A2F_SHORTS;                    //  3.67 MB
    float* pt  = (float*)(Btf + BTF_SHORTS);          // 14.16 MB

    hipMemsetAsync(out, 0, (size_t)PLANE * sizeof(float), stream);

    ln_kernel<<<SEQ / 16, 256, 0, stream>>>(hs, gamma, beta, A2f);
    wprep_kernel<<<dim3(DM / 32, NJ / 32), 256, 0, stream>>>(W, Btf);
    gemm_kernel<<<dim3(SEQ / 128, 7), 256, 0, stream>>>(A2f, Btf, b, pt);
    spring_kernel<<<dim3(SEQ / 256, NIMU, 2), 256, 0, stream>>>(pt, out);
    tail_kernel<<<(4 * PLANE + 255) / 256, 256, 0, stream>>>(pt, out);
}